// Round 22
// baseline (66.895 us; speedup 1.0000x reference)
//
#include <hip/hip_runtime.h>
#include <hip/hip_bf16.h>
#include <math.h>

#define BATCHES 8
#define SEQ 1024
#define DDIM 768
#define NPANEL 16         // 1024 / 64 row-panels (i8 path)
#define NK64 12           // 768 / 64 K-chunks (i8 path)
#define CHUNK_B 8192      // bytes per (panel,k64) chunk: q1 4096 + q2 4096
#define NK32 24           // bf16 fallback
#define QMAX 6.35f

typedef unsigned short u16;
typedef __attribute__((ext_vector_type(8))) short bf16x8;
typedef __attribute__((ext_vector_type(8))) unsigned short u16x8;
typedef __attribute__((ext_vector_type(4))) float f32x4;
typedef __attribute__((ext_vector_type(4))) int i32x4;

static __device__ __forceinline__ u16 f2bf(float x) {
    union { float f; unsigned u; } v; v.f = x;
    unsigned r = v.u + 0x7FFFu + ((v.u >> 16) & 1u);
    return (u16)(r >> 16);
}
static __device__ __forceinline__ float bf2f(u16 h) {
    union { float f; unsigned u; } v; v.u = ((unsigned)h) << 16; return v.f;
}

__device__ __forceinline__ void glds16(const void* g, void* l) {
    __builtin_amdgcn_global_load_lds(
        (const __attribute__((address_space(1))) void*)g,
        (__attribute__((address_space(3))) void*)l, 16, 0, 0);
}

// ---- Kernel A: fused quantize (fp32 -> i8 q1 + i8 q2, 64-row MFMA tiles) + proj ----
__global__ __launch_bounds__(256) void prep_i8(
    const float* __restrict__ S, const float* __restrict__ T,
    const float* __restrict__ W, const float* __restrict__ bcost,
    const float* __restrict__ temb, const int* __restrict__ task_id,
    unsigned char* __restrict__ Sg, unsigned char* __restrict__ Tg,
    float* __restrict__ sproj, float* __restrict__ tproj,
    float* __restrict__ cterm)
{
    int t = threadIdx.x;
    int g = blockIdx.x * 256 + t;
    int r  = g & 15;
    int kg = (g >> 4) & 3;
    int m  = (g >> 6) & 3;
    int x  = g >> 8;                 // 0..3071
    int ks = x % NK64;
    int y  = x / NK64;               // 0..511
    int p  = y & 15;
    int b  = (y >> 4) & 7;
    int tensor = y >> 7;

    int row_loc = p * 64 + m * 16 + r;           // 0..1023
    int row_glb = b * SEQ + row_loc;
    int col = ks * 64 + kg * 16;

    const float* src = (tensor ? T : S) + (size_t)row_glb * DDIM + col;
    float4 f0 = *(const float4*)(src);
    float4 f1 = *(const float4*)(src + 4);
    float4 f2 = *(const float4*)(src + 8);
    float4 f3 = *(const float4*)(src + 12);
    float4 w0 = *(const float4*)(W + col);
    float4 w1 = *(const float4*)(W + col + 4);
    float4 w2 = *(const float4*)(W + col + 8);
    float4 w3 = *(const float4*)(W + col + 12);

    float xv[16] = {f0.x,f0.y,f0.z,f0.w, f1.x,f1.y,f1.z,f1.w,
                    f2.x,f2.y,f2.z,f2.w, f3.x,f3.y,f3.z,f3.w};
    float wv[16] = {w0.x,w0.y,w0.z,w0.w, w1.x,w1.y,w1.z,w1.w,
                    w2.x,w2.y,w2.z,w2.w, w3.x,w3.y,w3.z,w3.w};

    // projection partial: wave lanes {r, r+16, r+32, r+48} share a row (kg 0..3)
    float pd = 0.f;
    #pragma unroll
    for (int e = 0; e < 16; ++e) pd = fmaf(xv[e], wv[e], pd);
    pd += __shfl_down(pd, 32);
    pd += __shfl_down(pd, 16);
    if ((t & 63) < 16)
        atomicAdd((tensor ? tproj : sproj) + row_glb, pd);   // 12 atomics/row

    const float s     = QMAX / 127.0f;
    const float inv_s = 127.0f / QMAX;
    const float inv_s2 = 252.0f / s;
    unsigned q1w[4] = {0,0,0,0}, q2w[4] = {0,0,0,0};
    #pragma unroll
    for (int e = 0; e < 16; ++e) {
        float v = xv[e];
        float q1f = rintf(v * inv_s);
        q1f = fminf(fmaxf(q1f, -127.f), 127.f);
        float rr = fmaf(-q1f, s, v);
        float q2f = rintf(rr * inv_s2);
        q2f = fminf(fmaxf(q2f, -126.f), 126.f);
        unsigned b1 = (unsigned)(unsigned char)(char)(int)q1f;
        unsigned b2 = (unsigned)(unsigned char)(char)(int)q2f;
        q1w[e >> 2] |= b1 << ((e & 3) * 8);
        q2w[e >> 2] |= b2 << ((e & 3) * 8);
    }
    unsigned char* dst = (tensor ? Tg : Sg)
        + (size_t)((b * NPANEL + p) * NK64 + ks) * CHUNK_B
        + (m * 1024 + kg * 256 + r * 16);
    *(uint4*)dst          = (uint4){q1w[0], q1w[1], q1w[2], q1w[3]};
    *(uint4*)(dst + 4096) = (uint4){q2w[0], q2w[1], q2w[2], q2w[3]};

    if (blockIdx.x == 0 && t < 64) {
        int tid = *task_id;
        float sacc = 0.f;
        #pragma unroll
        for (int d = t; d < DDIM; d += 64) sacc = fmaf(temb[tid * DDIM + d], W[d], sacc);
        #pragma unroll
        for (int o = 32; o; o >>= 1) sacc += __shfl_down(sacc, o);
        if (t == 0) *cterm = sacc + bcost[0];
    }
}

// -------- fallback proj kernel (small-ws path only) --------
__global__ __launch_bounds__(256) void proj_kernel(
    const float* __restrict__ S, const float* __restrict__ T,
    const float* __restrict__ W, const float* __restrict__ bcost,
    const float* __restrict__ temb, const int* __restrict__ task_id,
    float* __restrict__ sproj, float* __restrict__ tproj,
    float* __restrict__ cterm)
{
    int gw   = (blockIdx.x * blockDim.x + threadIdx.x) >> 6;
    int lane = threadIdx.x & 63;

    if (gw < 2 * BATCHES * SEQ) {
        const float* rowp = (gw < BATCHES * SEQ)
            ? S + (size_t)gw * DDIM
            : T + (size_t)(gw - BATCHES * SEQ) * DDIM;
        float s = 0.f;
        #pragma unroll
        for (int d = lane; d < DDIM; d += 64) s = fmaf(rowp[d], W[d], s);
        #pragma unroll
        for (int o = 32; o; o >>= 1) s += __shfl_down(s, o);
        if (lane == 0) {
            if (gw < BATCHES * SEQ) sproj[gw] = s;
            else                    tproj[gw - BATCHES * SEQ] = s;
        }
    }
    if (blockIdx.x == gridDim.x - 1 && (threadIdx.x >> 6) == 0) {
        int tid = *task_id;
        float s = 0.f;
        #pragma unroll
        for (int d = lane; d < DDIM; d += 64) s = fmaf(temb[tid * DDIM + d], W[d], s);
        #pragma unroll
        for (int o = 32; o; o >>= 1) s += __shfl_down(s, o);
        if (lane == 0) *cterm = s + bcost[0];
    }
}

// --- Kernel B: i8 MFMA GEMM, 32x64 wave-tiles; A direct-L2, B via LDS ---
// r21 + ONE change: the 8KB B-chunk (shared by all 4 waves) is staged once
// per block via global_load_lds (2 glds/wave) instead of being re-requested
// 4x from L2. Per-wave L2 requests/iter: 16 -> 6; block request bytes /2.
// Static ping-pong bufs; raw s_barrier + counted drain (only 2 glds pending).
__global__ __launch_bounds__(256, 4) void gemm_i8(
    const unsigned char* __restrict__ Sg, const unsigned char* __restrict__ Tg,
    _Float16* __restrict__ c0buf, double* __restrict__ batch_sums)
{
    __shared__ __align__(16) unsigned char bufA[8192];
    __shared__ __align__(16) unsigned char bufB[8192];
    __shared__ double red[8];

    const int t    = threadIdx.x;
    const int lane = t & 63;
    const int w    = t >> 6;

    // XCD swizzle: batch = blockIdx&7 (one batch per XCD)
    const int b   = blockIdx.x & 7;
    const int q   = blockIdx.x >> 3;         // 0..127
    const int bx  = q & 15;                  // 64-col panel, shared by 4 waves
    const int byh = ((q >> 4) << 2) + w;     // 0..31: 32-row half-panel per wave
    const int p   = byh >> 1;                // 64-row source panel
    const int h   = byh & 1;                 // which half of the panel

    i32x4 acc_hh[2][4], acc_x[2][4];
    #pragma unroll
    for (int m = 0; m < 2; ++m)
        #pragma unroll
        for (int n = 0; n < 4; ++n) {
            acc_hh[m][n] = (i32x4){0,0,0,0};
            acc_x[m][n]  = (i32x4){0,0,0,0};
        }

    const unsigned char* Achunk = Sg + (size_t)((b * NPANEL + p) * NK64) * CHUNK_B
                                + (h * 2) * 1024 + lane * 16;
    const unsigned char* Bchunk = Tg + (size_t)((b * NPANEL + bx) * NK64) * CHUNK_B
                                + w * 2048 + lane * 16;

    // wave w stages bytes [w*2048, w*2048+2048) of the 8KB B-chunk (2 glds)
    auto STAGE_B = [&](int ks, unsigned char* buf) {
        const unsigned char* src = Bchunk + (size_t)ks * CHUNK_B;
        glds16(src,        buf + w * 2048);
        glds16(src + 1024, buf + w * 2048 + 1024);
    };
    auto COMPUTE = [&](int ks, const unsigned char* buf) {
        const unsigned char* Ak = Achunk + (size_t)ks * CHUNK_B;
        i32x4 a1[2], a2[2], b1[4], b2[4];
        #pragma unroll
        for (int m = 0; m < 2; ++m) {
            a1[m] = *(const i32x4*)(Ak + m * 1024);
            a2[m] = *(const i32x4*)(Ak + 4096 + m * 1024);
        }
        #pragma unroll
        for (int n = 0; n < 4; ++n) {
            b1[n] = *(const i32x4*)(buf + n * 1024 + lane * 16);
            b2[n] = *(const i32x4*)(buf + 4096 + n * 1024 + lane * 16);
        }
        #pragma unroll
        for (int m = 0; m < 2; ++m)
            #pragma unroll
            for (int n = 0; n < 4; ++n) {
                acc_hh[m][n] = __builtin_amdgcn_mfma_i32_16x16x64_i8(a1[m], b1[n], acc_hh[m][n], 0, 0, 0);
                acc_x[m][n]  = __builtin_amdgcn_mfma_i32_16x16x64_i8(a1[m], b2[n], acc_x[m][n], 0, 0, 0);
                acc_x[m][n]  = __builtin_amdgcn_mfma_i32_16x16x64_i8(a2[m], b1[n], acc_x[m][n], 0, 0, 0);
            }
    };

    // 2-deep ping-pong: stage(next B) issued before compute(cur); the trailing
    // vmcnt(0) waits only those 2 glds (A loads already consumed by MFMA).
    STAGE_B(0, bufA);
    asm volatile("s_waitcnt vmcnt(0)" ::: "memory");
    __builtin_amdgcn_s_barrier();
    #pragma unroll 1
    for (int it = 0; it < NK64; it += 2) {
        STAGE_B(it + 1, bufB);
        COMPUTE(it, bufA);
        asm volatile("s_waitcnt vmcnt(0) lgkmcnt(0)" ::: "memory");
        __builtin_amdgcn_s_barrier();
        if (it + 2 < NK64) STAGE_B(it + 2, bufA);
        COMPUTE(it + 1, bufB);
        asm volatile("s_waitcnt vmcnt(0) lgkmcnt(0)" ::: "memory");
        __builtin_amdgcn_s_barrier();
    }

    // epilogue: reconstruct dots, c0 = (1 - cos)/2, store fp16, accumulate sums
    const float S2  = (QMAX / 127.0f) * (QMAX / 127.0f);
    const float S2F = S2 / 252.0f;
    float lsum = 0.f, lsq = 0.f;
    _Float16* cb = c0buf + (size_t)b * SEQ * SEQ;
    const int rbase = byh * 32;
    const int cbase = bx * 64;
    const int cr = lane >> 4;
    const int cc = lane & 15;
    #pragma unroll
    for (int m = 0; m < 2; ++m) {
        #pragma unroll
        for (int n = 0; n < 4; ++n) {
            int col = cbase + n * 16 + cc;
            #pragma unroll
            for (int j = 0; j < 4; ++j) {
                int row = rbase + m * 16 + cr * 4 + j;
                float d  = S2 * (float)acc_hh[m][n][j] + S2F * (float)acc_x[m][n][j];
                float c0 = 0.5f - 0.5f * __cosf(d);
                cb[(size_t)row * SEQ + col] = (_Float16)c0;
                lsum += c0;
                lsq  = fmaf(c0, c0, lsq);
            }
        }
    }

    double s = (double)lsum, q2 = (double)lsq;
    #pragma unroll
    for (int o = 32; o; o >>= 1) { s += __shfl_down(s, o); q2 += __shfl_down(q2, o); }
    if (lane == 0) { red[w] = s; red[4 + w] = q2; }
    __syncthreads();
    if (t == 0) {
        s  = red[0] + red[1] + red[2] + red[3];
        q2 = red[4] + red[5] + red[6] + red[7];
        atomicAdd(&batch_sums[b * 2 + 0], s);    // all 4 waves share b
        atomicAdd(&batch_sums[b * 2 + 1], q2);
    }
}

// --- fallback: bf16 hi/lo fused GEMM (small-ws only, 128^2, 512 blocks) ---
__global__ __launch_bounds__(256) void gemm_fused_bf16(
    const float* __restrict__ S, const float* __restrict__ T,
    float* __restrict__ out, double* __restrict__ batch_sums)
{
    __shared__ __align__(16) u16 lds[16384];
    __shared__ double red[8];

    const int t    = threadIdx.x;
    const int lane = t & 63;
    const int w    = t >> 6;
    const int wr   = w >> 1, wc = w & 1;

    int wg = (blockIdx.x & 7) * 64 + (blockIdx.x >> 3);
    const int b  = wg >> 6;
    const int by = (wg >> 3) & 7;
    const int bx = wg & 7;

    f32x4 acc[4][4];
    #pragma unroll
    for (int m = 0; m < 4; ++m)
        #pragma unroll
        for (int n = 0; n < 4; ++n) acc[m][n] = (f32x4){0.f, 0.f, 0.f, 0.f};

    const float* Sb = S + (size_t)b * SEQ * DDIM;
    const float* Tb = T + (size_t)b * SEQ * DDIM;
    const float* pa[2]; const float* pb[2];
    float4 ra[2][2], rb[2][2];
    #pragma unroll
    for (int i = 0; i < 2; ++i) {
        int g = t + i * 256;
        int m = g >> 6, kg = (g >> 4) & 3, r = g & 15;
        pa[i] = Sb + (size_t)(by * 128 + m * 16 + r) * DDIM + kg * 8;
        pb[i] = Tb + (size_t)(bx * 128 + m * 16 + r) * DDIM + kg * 8;
    }

    auto LOADREGS = [&](int ks) {
        #pragma unroll
        for (int i = 0; i < 2; ++i) {
            ra[i][0] = *(const float4*)(pa[i] + ks * 32);
            ra[i][1] = *(const float4*)(pa[i] + ks * 32 + 4);
            rb[i][0] = *(const float4*)(pb[i] + ks * 32);
            rb[i][1] = *(const float4*)(pb[i] + ks * 32 + 4);
        }
    };
    auto STAGE_FUSED = [&]() {
        #pragma unroll
        for (int i = 0; i < 2; ++i) {
            int g = t + i * 256;
            float xa[8] = {ra[i][0].x, ra[i][0].y, ra[i][0].z, ra[i][0].w,
                           ra[i][1].x, ra[i][1].y, ra[i][1].z, ra[i][1].w};
            float xb[8] = {rb[i][0].x, rb[i][0].y, rb[i][0].z, rb[i][0].w,
                           rb[i][1].x, rb[i][1].y, rb[i][1].z, rb[i][1].w};
            u16x8 ah, al, bh, bl;
            #pragma unroll
            for (int e = 0; e < 8; ++e) {
                u16 h = f2bf(xa[e]); ah[e] = h; al[e] = f2bf(xa[e] - bf2f(h));
                u16 g2 = f2bf(xb[e]); bh[e] = g2; bl[e] = f2bf(xb[e] - bf2f(g2));
            }
            *(u16x8*)&lds[(size_t)g * 8]         = ah;
            *(u16x8*)&lds[4096 + (size_t)g * 8]  = al;
            *(u16x8*)&lds[8192 + (size_t)g * 8]  = bh;
            *(u16x8*)&lds[12288 + (size_t)g * 8] = bl;
        }
    };
    auto COMPUTE = [&]() {
        const u16* L = &lds[0];
        bf16x8 ah[4], al[4], bh[4], bl[4];
        #pragma unroll
        for (int m = 0; m < 4; ++m) {
            int sm = wr * 4 + m;
            ah[m] = *(const bf16x8*)(L + sm * 512 + lane * 8);
            al[m] = *(const bf16x8*)(L + 4096 + sm * 512 + lane * 8);
        }
        #pragma unroll
        for (int n = 0; n < 4; ++n) {
            int sn = wc * 4 + n;
            bh[n] = *(const bf16x8*)(L + 8192 + sn * 512 + lane * 8);
            bl[n] = *(const bf16x8*)(L + 12288 + sn * 512 + lane * 8);
        }
        #pragma unroll
        for (int m = 0; m < 4; ++m)
            #pragma unroll
            for (int n = 0; n < 4; ++n) {
                acc[m][n] = __builtin_amdgcn_mfma_f32_16x16x32_bf16(ah[m], bh[n], acc[m][n], 0, 0, 0);
                acc[m][n] = __builtin_amdgcn_mfma_f32_16x16x32_bf16(ah[m], bl[n], acc[m][n], 0, 0, 0);
                acc[m][n] = __builtin_amdgcn_mfma_f32_16x16x32_bf16(al[m], bh[n], acc[m][n], 0, 0, 0);
            }
    };

    LOADREGS(0);
    for (int ks = 0; ks < NK32; ++ks) {
        STAGE_FUSED();
        __syncthreads();
        if (ks + 1 < NK32) LOADREGS(ks + 1);
        COMPUTE();
        __syncthreads();
    }

    float lsum = 0.f, lsq = 0.f;
    float* outb = out + (size_t)b * SEQ * SEQ;
    const int rbase = by * 128 + wr * 64;
    const int cbase = bx * 128 + wc * 64;
    const int cr = lane >> 4;
    const int cc = lane & 15;
    #pragma unroll
    for (int m = 0; m < 4; ++m) {
        #pragma unroll
        for (int n = 0; n < 4; ++n) {
            int col = cbase + n * 16 + cc;
            #pragma unroll
            for (int j = 0; j < 4; ++j) {
                int row = rbase + m * 16 + cr * 4 + j;
                float d  = acc[m][n][j];
                float c0 = 0.5f - 0.5f * __cosf(d);
                outb[(size_t)row * SEQ + col] = c0;
                lsum += c0;
                lsq  = fmaf(c0, c0, lsq);
            }
        }
    }

    double s = (double)lsum, q = (double)lsq;
    #pragma unroll
    for (int o = 32; o; o >>= 1) { s += __shfl_down(s, o); q += __shfl_down(q, o); }
    if (lane == 0) { red[w] = s; red[4 + w] = q; }
    __syncthreads();
    if (t == 0) {
        s = red[0] + red[1] + red[2] + red[3];
        q = red[4] + red[5] + red[6] + red[7];
        atomicAdd(&batch_sums[b * 2 + 0], s);
        atomicAdd(&batch_sums[b * 2 + 1], q);
    }
}

// ---------------- finalize (fp16 source, big-ws path) ----------------
__global__ __launch_bounds__(256) void finalize_half(
    float* __restrict__ out, const _Float16* __restrict__ c0buf,
    const double* __restrict__ batch_sums,
    const float* __restrict__ sproj, const float* __restrict__ tproj,
    const float* __restrict__ cterm_p, const float* __restrict__ alpha_p)
{
    const double n = (double)SEQ * (double)SEQ;
    size_t idx8 = (size_t)blockIdx.x * blockDim.x + threadIdx.x;
    size_t base = idx8 * 8;
    int batch = (int)(base >> 20);
    int rem   = (int)(base & ((SEQ * SEQ) - 1));
    int srow  = rem >> 10;
    int tcol  = rem & (SEQ - 1);

    double sum = batch_sums[batch * 2 + 0];
    double sq  = batch_sums[batch * 2 + 1];
    double var = (sq - sum * sum / n) / (n - 1.0);
    float inv_std = (float)(1.0 / sqrt(var));

    float alpha = *alpha_p;
    float ct    = *cterm_p;
    float sp    = sproj[batch * SEQ + srow] + ct;
    float4 tp0  = *(const float4*)&tproj[batch * SEQ + tcol];
    float4 tp1  = *(const float4*)&tproj[batch * SEQ + tcol + 4];

    _Float16 h[8];
    *(uint4*)h = *(const uint4*)(c0buf + base);
    float tps[8] = {tp0.x, tp0.y, tp0.z, tp0.w, tp1.x, tp1.y, tp1.z, tp1.w};
    float r[8];
    #pragma unroll
    for (int e = 0; e < 8; ++e) {
        float x = (float)h[e] * inv_std;
        float g = __expf(-0.5f * x * x);
        float z = sp + tps[e];
        float cd = 1.f / (1.f + __expf(-z));
        r[e] = alpha * (g + cd);
    }
    *(float4*)&out[base]     = (float4){r[0], r[1], r[2], r[3]};
    *(float4*)&out[base + 4] = (float4){r[4], r[5], r[6], r[7]};
}

// ---------------- finalize (f32 in-place, fallback path) ----------------
__global__ __launch_bounds__(256) void finalize_f32(
    float* __restrict__ out, const double* __restrict__ batch_sums,
    const float* __restrict__ sproj, const float* __restrict__ tproj,
    const float* __restrict__ cterm_p, const float* __restrict__ alpha_p)
{
    const double n = (double)SEQ * (double)SEQ;
    size_t idx4 = (size_t)blockIdx.x * blockDim.x + threadIdx.x;
    size_t base = idx4 * 4;
    int batch = (int)(base >> 20);
    int rem   = (int)(base & ((SEQ * SEQ) - 1));
    int srow  = rem >> 10;
    int tcol  = rem & (SEQ - 1);

    double sum = batch_sums[batch * 2 + 0];
    double sq  = batch_sums[batch * 2 + 1];
    double var = (sq - sum * sum / n) / (n - 1.0);
    float inv_std = (float)(1.0 / sqrt(var));

    float alpha = *alpha_p;
    float ct    = *cterm_p;
    float sp    = sproj[batch * SEQ + srow];
    float4 tp   = *(const float4*)&tproj[batch * SEQ + tcol];
    float4 c    = *(float4*)&out[base];

    float4 r;
    { float x = c.x * inv_std; float g = __expf(-0.5f * x * x);
      float z = sp + tp.x + ct; float cd = 1.f / (1.f + __expf(-z)); r.x = alpha * (g + cd); }
    { float x = c.y * inv_std; float g = __expf(-0.5f * x * x);
      float z = sp + tp.y + ct; float cd = 1.f / (1.f + __expf(-z)); r.y = alpha * (g + cd); }
    { float x = c.z * inv_std; float g = __expf(-0.5f * x * x);
      float z = sp + tp.z + ct; float cd = 1.f / (1.f + __expf(-z)); r.z = alpha * (g + cd); }
    { float x = c.w * inv_std; float g = __expf(-0.5f * x * x);
      float z = sp + tp.w + ct; float cd = 1.f / (1.f + __expf(-z)); r.w = alpha * (g + cd); }
    *(float4*)&out[base] = r;
}

// ---------------- launch ----------------
extern "C" void kernel_launch(void* const* d_in, const int* in_sizes, int n_in,
                              void* d_out, int out_size, void* d_ws, size_t ws_size,
                              hipStream_t stream) {
    const float* S      = (const float*)d_in[0];
    const float* T      = (const float*)d_in[1];
    const float* W      = (const float*)d_in[2];
    const float* bcost  = (const float*)d_in[3];
    const float* temb   = (const float*)d_in[4];
    const float* alpha  = (const float*)d_in[5];
    const int*   taskid = (const int*)d_in[6];
    float* out = (float*)d_out;

    double* batch_sums = (double*)d_ws;                 // 16 doubles @ 0
    float*  sproj = (float*)((char*)d_ws + 128);        // 8192 floats
    float*  tproj = sproj + BATCHES * SEQ;              // 8192 floats
    float*  cterm = tproj + BATCHES * SEQ;              // 1 float

    const size_t ZERO_BYTES = 128 + sizeof(float) * (2 * BATCHES * SEQ + 1);
    const size_t SMALL = (size_t)1 << 20;
    const size_t CONV_B = (size_t)BATCHES * NPANEL * NK64 * CHUNK_B;  // per tensor
    const size_t C0_B   = (size_t)BATCHES * SEQ * SEQ * 2;            // fp16 c0
    const size_t NEEDED = SMALL + 2 * CONV_B + C0_B;
    unsigned char* Sg = (unsigned char*)d_ws + SMALL;
    unsigned char* Tg = Sg + CONV_B;
    _Float16* c0buf = (_Float16*)(Tg + CONV_B);

    hipMemsetAsync(d_ws, 0, ZERO_BYTES, stream);

    if (ws_size >= NEEDED) {
        int nblk = (2 * BATCHES * NPANEL * NK64 * 256) / 256;   // 3072
        prep_i8<<<nblk, 256, 0, stream>>>(S, T, W, bcost, temb, taskid,
                                          Sg, Tg, sproj, tproj, cterm);
        gemm_i8<<<1024, 256, 0, stream>>>(Sg, Tg, c0buf, batch_sums);
        int nfin = (BATCHES * SEQ * SEQ) / (256 * 8);
        finalize_half<<<nfin, 256, 0, stream>>>(out, c0buf, batch_sums,
                                                sproj, tproj, cterm, alpha);
    } else {
        proj_kernel<<<4097, 256, 0, stream>>>(S, T, W, bcost, temb, taskid,
                                              sproj, tproj, cterm);
        gemm_fused_bf16<<<512, 256, 0, stream>>>(S, T, out, batch_sums);
        int nfin = (BATCHES * SEQ * SEQ) / (256 * 4);
        finalize_f32<<<nfin, 256, 0, stream>>>(out, batch_sums, sproj, tproj,
                                               cterm, alpha);
    }
}

// Round 24
// 65.513 us; speedup vs baseline: 1.0211x; 1.0211x over previous
//
#include <hip/hip_runtime.h>
#include <hip/hip_bf16.h>
#include <math.h>

#define BATCHES 8
#define SEQ 1024
#define DDIM 768
#define NPANEL 16         // 1024 / 64 row-panels (i8 path)
#define NK64 12           // 768 / 64 K-chunks (i8 path)
#define CHUNK_B 8192      // bytes per (panel,k64) chunk: q1 4096 + q2 4096
#define NK32 24           // bf16 fallback
#define QMAX 6.35f

typedef unsigned short u16;
typedef __attribute__((ext_vector_type(8))) short bf16x8;
typedef __attribute__((ext_vector_type(8))) unsigned short u16x8;
typedef __attribute__((ext_vector_type(4))) float f32x4;
typedef __attribute__((ext_vector_type(4))) int i32x4;

static __device__ __forceinline__ u16 f2bf(float x) {
    union { float f; unsigned u; } v; v.f = x;
    unsigned r = v.u + 0x7FFFu + ((v.u >> 16) & 1u);
    return (u16)(r >> 16);
}
static __device__ __forceinline__ float bf2f(u16 h) {
    union { float f; unsigned u; } v; v.u = ((unsigned)h) << 16; return v.f;
}

// ---- Kernel A: fused quantize (fp32 -> i8 q1 + i8 q2, 64-row MFMA tiles) + proj ----
__global__ __launch_bounds__(256) void prep_i8(
    const float* __restrict__ S, const float* __restrict__ T,
    const float* __restrict__ W, const float* __restrict__ bcost,
    const float* __restrict__ temb, const int* __restrict__ task_id,
    unsigned char* __restrict__ Sg, unsigned char* __restrict__ Tg,
    float* __restrict__ sproj, float* __restrict__ tproj,
    float* __restrict__ cterm)
{
    int t = threadIdx.x;
    int g = blockIdx.x * 256 + t;
    int r  = g & 15;
    int kg = (g >> 4) & 3;
    int m  = (g >> 6) & 3;
    int x  = g >> 8;                 // 0..3071
    int ks = x % NK64;
    int y  = x / NK64;               // 0..511
    int p  = y & 15;
    int b  = (y >> 4) & 7;
    int tensor = y >> 7;

    int row_loc = p * 64 + m * 16 + r;           // 0..1023
    int row_glb = b * SEQ + row_loc;
    int col = ks * 64 + kg * 16;

    const float* src = (tensor ? T : S) + (size_t)row_glb * DDIM + col;
    float4 f0 = *(const float4*)(src);
    float4 f1 = *(const float4*)(src + 4);
    float4 f2 = *(const float4*)(src + 8);
    float4 f3 = *(const float4*)(src + 12);
    float4 w0 = *(const float4*)(W + col);
    float4 w1 = *(const float4*)(W + col + 4);
    float4 w2 = *(const float4*)(W + col + 8);
    float4 w3 = *(const float4*)(W + col + 12);

    float xv[16] = {f0.x,f0.y,f0.z,f0.w, f1.x,f1.y,f1.z,f1.w,
                    f2.x,f2.y,f2.z,f2.w, f3.x,f3.y,f3.z,f3.w};
    float wv[16] = {w0.x,w0.y,w0.z,w0.w, w1.x,w1.y,w1.z,w1.w,
                    w2.x,w2.y,w2.z,w2.w, w3.x,w3.y,w3.z,w3.w};

    // projection partial: wave lanes {r, r+16, r+32, r+48} share a row (kg 0..3)
    float pd = 0.f;
    #pragma unroll
    for (int e = 0; e < 16; ++e) pd = fmaf(xv[e], wv[e], pd);
    pd += __shfl_down(pd, 32);
    pd += __shfl_down(pd, 16);
    if ((t & 63) < 16)
        atomicAdd((tensor ? tproj : sproj) + row_glb, pd);   // 12 atomics/row

    const float s     = QMAX / 127.0f;
    const float inv_s = 127.0f / QMAX;
    const float inv_s2 = 252.0f / s;
    unsigned q1w[4] = {0,0,0,0}, q2w[4] = {0,0,0,0};
    #pragma unroll
    for (int e = 0; e < 16; ++e) {
        float v = xv[e];
        float q1f = rintf(v * inv_s);
        q1f = fminf(fmaxf(q1f, -127.f), 127.f);
        float rr = fmaf(-q1f, s, v);
        float q2f = rintf(rr * inv_s2);
        q2f = fminf(fmaxf(q2f, -126.f), 126.f);
        unsigned b1 = (unsigned)(unsigned char)(char)(int)q1f;
        unsigned b2 = (unsigned)(unsigned char)(char)(int)q2f;
        q1w[e >> 2] |= b1 << ((e & 3) * 8);
        q2w[e >> 2] |= b2 << ((e & 3) * 8);
    }
    unsigned char* dst = (tensor ? Tg : Sg)
        + (size_t)((b * NPANEL + p) * NK64 + ks) * CHUNK_B
        + (m * 1024 + kg * 256 + r * 16);
    *(uint4*)dst          = (uint4){q1w[0], q1w[1], q1w[2], q1w[3]};
    *(uint4*)(dst + 4096) = (uint4){q2w[0], q2w[1], q2w[2], q2w[3]};

    if (blockIdx.x == 0 && t < 64) {
        int tid = *task_id;
        float sacc = 0.f;
        #pragma unroll
        for (int d = t; d < DDIM; d += 64) sacc = fmaf(temb[tid * DDIM + d], W[d], sacc);
        #pragma unroll
        for (int o = 32; o; o >>= 1) sacc += __shfl_down(sacc, o);
        if (t == 0) *cterm = sacc + bcost[0];
    }
}

// -------- fallback proj kernel (small-ws path only) --------
__global__ __launch_bounds__(256) void proj_kernel(
    const float* __restrict__ S, const float* __restrict__ T,
    const float* __restrict__ W, const float* __restrict__ bcost,
    const float* __restrict__ temb, const int* __restrict__ task_id,
    float* __restrict__ sproj, float* __restrict__ tproj,
    float* __restrict__ cterm)
{
    int gw   = (blockIdx.x * blockDim.x + threadIdx.x) >> 6;
    int lane = threadIdx.x & 63;

    if (gw < 2 * BATCHES * SEQ) {
        const float* rowp = (gw < BATCHES * SEQ)
            ? S + (size_t)gw * DDIM
            : T + (size_t)(gw - BATCHES * SEQ) * DDIM;
        float s = 0.f;
        #pragma unroll
        for (int d = lane; d < DDIM; d += 64) s = fmaf(rowp[d], W[d], s);
        #pragma unroll
        for (int o = 32; o; o >>= 1) s += __shfl_down(s, o);
        if (lane == 0) {
            if (gw < BATCHES * SEQ) sproj[gw] = s;
            else                    tproj[gw - BATCHES * SEQ] = s;
        }
    }
    if (blockIdx.x == gridDim.x - 1 && (threadIdx.x >> 6) == 0) {
        int tid = *task_id;
        float s = 0.f;
        #pragma unroll
        for (int d = lane; d < DDIM; d += 64) s = fmaf(temb[tid * DDIM + d], W[d], s);
        #pragma unroll
        for (int o = 32; o; o >>= 1) s += __shfl_down(s, o);
        if (lane == 0) *cterm = s + bcost[0];
    }
}

// --- Kernel B: i8 MFMA GEMM, 32x64 wave-tiles, direct L2 loads (r21 stable) ---
__global__ __launch_bounds__(256, 4) void gemm_i8(
    const unsigned char* __restrict__ Sg, const unsigned char* __restrict__ Tg,
    _Float16* __restrict__ c0buf, double* __restrict__ batch_sums)
{
    __shared__ double red[8];

    const int t    = threadIdx.x;
    const int lane = t & 63;
    const int w    = t >> 6;

    // XCD swizzle: batch = blockIdx&7 (one batch per XCD)
    const int b   = blockIdx.x & 7;
    const int q   = blockIdx.x >> 3;         // 0..127
    const int bx  = q & 15;                  // 64-col panel, shared by 4 waves
    const int byh = ((q >> 4) << 2) + w;     // 0..31: 32-row half-panel per wave
    const int p   = byh >> 1;                // 64-row source panel
    const int h   = byh & 1;                 // which half of the panel

    i32x4 acc_hh[2][4], acc_x[2][4];
    #pragma unroll
    for (int m = 0; m < 2; ++m)
        #pragma unroll
        for (int n = 0; n < 4; ++n) {
            acc_hh[m][n] = (i32x4){0,0,0,0};
            acc_x[m][n]  = (i32x4){0,0,0,0};
        }

    const unsigned char* Achunk = Sg + (size_t)((b * NPANEL + p) * NK64) * CHUNK_B
                                + (h * 2) * 1024 + lane * 16;
    const unsigned char* Bchunk = Tg + (size_t)((b * NPANEL + bx) * NK64) * CHUNK_B
                                + lane * 16;

    #pragma unroll 1
    for (int ks = 0; ks < NK64; ++ks) {
        const unsigned char* Ak = Achunk + (size_t)ks * CHUNK_B;
        const unsigned char* Bk = Bchunk + (size_t)ks * CHUNK_B;
        i32x4 a1[2], a2[2], b1[4], b2[4];
        #pragma unroll
        for (int m = 0; m < 2; ++m) {
            a1[m] = *(const i32x4*)(Ak + m * 1024);
            a2[m] = *(const i32x4*)(Ak + 4096 + m * 1024);
        }
        #pragma unroll
        for (int n = 0; n < 4; ++n) {
            b1[n] = *(const i32x4*)(Bk + n * 1024);
            b2[n] = *(const i32x4*)(Bk + 4096 + n * 1024);
        }
        #pragma unroll
        for (int m = 0; m < 2; ++m)
            #pragma unroll
            for (int n = 0; n < 4; ++n) {
                acc_hh[m][n] = __builtin_amdgcn_mfma_i32_16x16x64_i8(a1[m], b1[n], acc_hh[m][n], 0, 0, 0);
                acc_x[m][n]  = __builtin_amdgcn_mfma_i32_16x16x64_i8(a1[m], b2[n], acc_x[m][n], 0, 0, 0);
                acc_x[m][n]  = __builtin_amdgcn_mfma_i32_16x16x64_i8(a2[m], b1[n], acc_x[m][n], 0, 0, 0);
            }
        // lockstep: raw barrier, no memory drain (registers only)
        __builtin_amdgcn_s_barrier();
    }

    // epilogue: reconstruct dots, c0 = (1 - cos)/2, store fp16, accumulate sums
    const float S2  = (QMAX / 127.0f) * (QMAX / 127.0f);
    const float S2F = S2 / 252.0f;
    float lsum = 0.f, lsq = 0.f;
    _Float16* cb = c0buf + (size_t)b * SEQ * SEQ;
    const int rbase = byh * 32;
    const int cbase = bx * 64;
    const int cr = lane >> 4;
    const int cc = lane & 15;
    #pragma unroll
    for (int m = 0; m < 2; ++m) {
        #pragma unroll
        for (int n = 0; n < 4; ++n) {
            int col = cbase + n * 16 + cc;
            #pragma unroll
            for (int j = 0; j < 4; ++j) {
                int row = rbase + m * 16 + cr * 4 + j;
                float d  = S2 * (float)acc_hh[m][n][j] + S2F * (float)acc_x[m][n][j];
                float c0 = 0.5f - 0.5f * __cosf(d);
                cb[(size_t)row * SEQ + col] = (_Float16)c0;
                lsum += c0;
                lsq  = fmaf(c0, c0, lsq);
            }
        }
    }

    double s = (double)lsum, q2 = (double)lsq;
    #pragma unroll
    for (int o = 32; o; o >>= 1) { s += __shfl_down(s, o); q2 += __shfl_down(q2, o); }
    if (lane == 0) { red[w] = s; red[4 + w] = q2; }
    __syncthreads();
    if (t == 0) {
        s  = red[0] + red[1] + red[2] + red[3];
        q2 = red[4] + red[5] + red[6] + red[7];
        atomicAdd(&batch_sums[b * 2 + 0], s);    // all 4 waves share b
        atomicAdd(&batch_sums[b * 2 + 1], q2);
    }
}

// --- fallback: bf16 hi/lo fused GEMM (small-ws only, 128^2, 512 blocks) ---
__global__ __launch_bounds__(256) void gemm_fused_bf16(
    const float* __restrict__ S, const float* __restrict__ T,
    float* __restrict__ out, double* __restrict__ batch_sums)
{
    __shared__ __align__(16) u16 lds[16384];
    __shared__ double red[8];

    const int t    = threadIdx.x;
    const int lane = t & 63;
    const int w    = t >> 6;
    const int wr   = w >> 1, wc = w & 1;

    int wg = (blockIdx.x & 7) * 64 + (blockIdx.x >> 3);
    const int b  = wg >> 6;
    const int by = (wg >> 3) & 7;
    const int bx = wg & 7;

    f32x4 acc[4][4];
    #pragma unroll
    for (int m = 0; m < 4; ++m)
        #pragma unroll
        for (int n = 0; n < 4; ++n) acc[m][n] = (f32x4){0.f, 0.f, 0.f, 0.f};

    const float* Sb = S + (size_t)b * SEQ * DDIM;
    const float* Tb = T + (size_t)b * SEQ * DDIM;
    const float* pa[2]; const float* pb[2];
    float4 ra[2][2], rb[2][2];
    #pragma unroll
    for (int i = 0; i < 2; ++i) {
        int g = t + i * 256;
        int m = g >> 6, kg = (g >> 4) & 3, r = g & 15;
        pa[i] = Sb + (size_t)(by * 128 + m * 16 + r) * DDIM + kg * 8;
        pb[i] = Tb + (size_t)(bx * 128 + m * 16 + r) * DDIM + kg * 8;
    }

    auto LOADREGS = [&](int ks) {
        #pragma unroll
        for (int i = 0; i < 2; ++i) {
            ra[i][0] = *(const float4*)(pa[i] + ks * 32);
            ra[i][1] = *(const float4*)(pa[i] + ks * 32 + 4);
            rb[i][0] = *(const float4*)(pb[i] + ks * 32);
            rb[i][1] = *(const float4*)(pb[i] + ks * 32 + 4);
        }
    };
    auto STAGE_FUSED = [&]() {
        #pragma unroll
        for (int i = 0; i < 2; ++i) {
            int g = t + i * 256;
            float xa[8] = {ra[i][0].x, ra[i][0].y, ra[i][0].z, ra[i][0].w,
                           ra[i][1].x, ra[i][1].y, ra[i][1].z, ra[i][1].w};
            float xb[8] = {rb[i][0].x, rb[i][0].y, rb[i][0].z, rb[i][0].w,
                           rb[i][1].x, rb[i][1].y, rb[i][1].z, rb[i][1].w};
            u16x8 ah, al, bh, bl;
            #pragma unroll
            for (int e = 0; e < 8; ++e) {
                u16 h = f2bf(xa[e]); ah[e] = h; al[e] = f2bf(xa[e] - bf2f(h));
                u16 g2 = f2bf(xb[e]); bh[e] = g2; bl[e] = f2bf(xb[e] - bf2f(g2));
            }
            *(u16x8*)&lds[(size_t)g * 8]         = ah;
            *(u16x8*)&lds[4096 + (size_t)g * 8]  = al;
            *(u16x8*)&lds[8192 + (size_t)g * 8]  = bh;
            *(u16x8*)&lds[12288 + (size_t)g * 8] = bl;
        }
    };
    auto COMPUTE = [&]() {
        const u16* L = &lds[0];
        bf16x8 ah[4], al[4], bh[4], bl[4];
        #pragma unroll
        for (int m = 0; m < 4; ++m) {
            int sm = wr * 4 + m;
            ah[m] = *(const bf16x8*)(L + sm * 512 + lane * 8);
            al[m] = *(const bf16x8*)(L + 4096 + sm * 512 + lane * 8);
        }
        #pragma unroll
        for (int n = 0; n < 4; ++n) {
            int sn = wc * 4 + n;
            bh[n] = *(const bf16x8*)(L + 8192 + sn * 512 + lane * 8);
            bl[n] = *(const bf16x8*)(L + 12288 + sn * 512 + lane * 8);
        }
        #pragma unroll
        for (int m = 0; m < 4; ++m)
            #pragma unroll
            for (int n = 0; n < 4; ++n) {
                acc[m][n] = __builtin_amdgcn_mfma_f32_16x16x32_bf16(ah[m], bh[n], acc[m][n], 0, 0, 0);
                acc[m][n] = __builtin_amdgcn_mfma_f32_16x16x32_bf16(ah[m], bl[n], acc[m][n], 0, 0, 0);
                acc[m][n] = __builtin_amdgcn_mfma_f32_16x16x32_bf16(al[m], bh[n], acc[m][n], 0, 0, 0);
            }
    };

    LOADREGS(0);
    for (int ks = 0; ks < NK32; ++ks) {
        STAGE_FUSED();
        __syncthreads();
        if (ks + 1 < NK32) LOADREGS(ks + 1);
        COMPUTE();
        __syncthreads();
    }

    float lsum = 0.f, lsq = 0.f;
    float* outb = out + (size_t)b * SEQ * SEQ;
    const int rbase = by * 128 + wr * 64;
    const int cbase = bx * 128 + wc * 64;
    const int cr = lane >> 4;
    const int cc = lane & 15;
    #pragma unroll
    for (int m = 0; m < 4; ++m) {
        #pragma unroll
        for (int n = 0; n < 4; ++n) {
            int col = cbase + n * 16 + cc;
            #pragma unroll
            for (int j = 0; j < 4; ++j) {
                int row = rbase + m * 16 + cr * 4 + j;
                float d  = acc[m][n][j];
                float c0 = 0.5f - 0.5f * __cosf(d);
                outb[(size_t)row * SEQ + col] = c0;
                lsum += c0;
                lsq  = fmaf(c0, c0, lsq);
            }
        }
    }

    double s = (double)lsum, q = (double)lsq;
    #pragma unroll
    for (int o = 32; o; o >>= 1) { s += __shfl_down(s, o); q += __shfl_down(q, o); }
    if (lane == 0) { red[w] = s; red[4 + w] = q; }
    __syncthreads();
    if (t == 0) {
        s = red[0] + red[1] + red[2] + red[3];
        q = red[4] + red[5] + red[6] + red[7];
        atomicAdd(&batch_sums[b * 2 + 0], s);
        atomicAdd(&batch_sums[b * 2 + 1], q);
    }
}

// ---------------- finalize (fp16 source, big-ws path) ----------------
__global__ __launch_bounds__(256) void finalize_half(
    float* __restrict__ out, const _Float16* __restrict__ c0buf,
    const double* __restrict__ batch_sums,
    const float* __restrict__ sproj, const float* __restrict__ tproj,
    const float* __restrict__ cterm_p, const float* __restrict__ alpha_p)
{
    const double n = (double)SEQ * (double)SEQ;
    size_t idx8 = (size_t)blockIdx.x * blockDim.x + threadIdx.x;
    size_t base = idx8 * 8;
    int batch = (int)(base >> 20);
    int rem   = (int)(base & ((SEQ * SEQ) - 1));
    int srow  = rem >> 10;
    int tcol  = rem & (SEQ - 1);

    double sum = batch_sums[batch * 2 + 0];
    double sq  = batch_sums[batch * 2 + 1];
    double var = (sq - sum * sum / n) / (n - 1.0);
    float inv_std = (float)(1.0 / sqrt(var));

    float alpha = *alpha_p;
    float ct    = *cterm_p;
    float sp    = sproj[batch * SEQ + srow] + ct;
    float4 tp0  = *(const float4*)&tproj[batch * SEQ + tcol];
    float4 tp1  = *(const float4*)&tproj[batch * SEQ + tcol + 4];

    _Float16 h[8];
    *(uint4*)h = *(const uint4*)(c0buf + base);
    float tps[8] = {tp0.x, tp0.y, tp0.z, tp0.w, tp1.x, tp1.y, tp1.z, tp1.w};
    float r[8];
    #pragma unroll
    for (int e = 0; e < 8; ++e) {
        float x = (float)h[e] * inv_std;
        float g = __expf(-0.5f * x * x);
        float z = sp + tps[e];
        float cd = 1.f / (1.f + __expf(-z));
        r[e] = alpha * (g + cd);
    }
    *(float4*)&out[base]     = (float4){r[0], r[1], r[2], r[3]};
    *(float4*)&out[base + 4] = (float4){r[4], r[5], r[6], r[7]};
}

// ---------------- finalize (f32 in-place, fallback path) ----------------
__global__ __launch_bounds__(256) void finalize_f32(
    float* __restrict__ out, const double* __restrict__ batch_sums,
    const float* __restrict__ sproj, const float* __restrict__ tproj,
    const float* __restrict__ cterm_p, const float* __restrict__ alpha_p)
{
    const double n = (double)SEQ * (double)SEQ;
    size_t idx4 = (size_t)blockIdx.x * blockDim.x + threadIdx.x;
    size_t base = idx4 * 4;
    int batch = (int)(base >> 20);
    int rem   = (int)(base & ((SEQ * SEQ) - 1));
    int srow  = rem >> 10;
    int tcol  = rem & (SEQ - 1);

    double sum = batch_sums[batch * 2 + 0];
    double sq  = batch_sums[batch * 2 + 1];
    double var = (sq - sum * sum / n) / (n - 1.0);
    float inv_std = (float)(1.0 / sqrt(var));

    float alpha = *alpha_p;
    float ct    = *cterm_p;
    float sp    = sproj[batch * SEQ + srow];
    float4 tp   = *(const float4*)&tproj[batch * SEQ + tcol];
    float4 c    = *(float4*)&out[base];

    float4 r;
    { float x = c.x * inv_std; float g = __expf(-0.5f * x * x);
      float z = sp + tp.x + ct; float cd = 1.f / (1.f + __expf(-z)); r.x = alpha * (g + cd); }
    { float x = c.y * inv_std; float g = __expf(-0.5f * x * x);
      float z = sp + tp.y + ct; float cd = 1.f / (1.f + __expf(-z)); r.y = alpha * (g + cd); }
    { float x = c.z * inv_std; float g = __expf(-0.5f * x * x);
      float z = sp + tp.z + ct; float cd = 1.f / (1.f + __expf(-z)); r.z = alpha * (g + cd); }
    { float x = c.w * inv_std; float g = __expf(-0.5f * x * x);
      float z = sp + tp.w + ct; float cd = 1.f / (1.f + __expf(-z)); r.w = alpha * (g + cd); }
    *(float4*)&out[base] = r;
}

// ---------------- launch ----------------
extern "C" void kernel_launch(void* const* d_in, const int* in_sizes, int n_in,
                              void* d_out, int out_size, void* d_ws, size_t ws_size,
                              hipStream_t stream) {
    const float* S      = (const float*)d_in[0];
    const float* T      = (const float*)d_in[1];
    const float* W      = (const float*)d_in[2];
    const float* bcost  = (const float*)d_in[3];
    const float* temb   = (const float*)d_in[4];
    const float* alpha  = (const float*)d_in[5];
    const int*   taskid = (const int*)d_in[6];
    float* out = (float*)d_out;

    double* batch_sums = (double*)d_ws;                 // 16 doubles @ 0
    float*  sproj = (float*)((char*)d_ws + 128);        // 8192 floats
    float*  tproj = sproj + BATCHES * SEQ;              // 8192 floats
    float*  cterm = tproj + BATCHES * SEQ;              // 1 float

    const size_t ZERO_BYTES = 128 + sizeof(float) * (2 * BATCHES * SEQ + 1);
    const size_t SMALL = (size_t)1 << 20;
    const size_t CONV_B = (size_t)BATCHES * NPANEL * NK64 * CHUNK_B;  // per tensor
    const size_t C0_B   = (size_t)BATCHES * SEQ * SEQ * 2;            // fp16 c0
    const size_t NEEDED = SMALL + 2 * CONV_B + C0_B;
    unsigned char* Sg = (unsigned char*)d_ws + SMALL;
    unsigned char* Tg = Sg + CONV_B;
    _Float16* c0buf = (_Float16*)(Tg + CONV_B);

    hipMemsetAsync(d_ws, 0, ZERO_BYTES, stream);

    if (ws_size >= NEEDED) {
        int nblk = (2 * BATCHES * NPANEL * NK64 * 256) / 256;   // 3072
        prep_i8<<<nblk, 256, 0, stream>>>(S, T, W, bcost, temb, taskid,
                                          Sg, Tg, sproj, tproj, cterm);
        gemm_i8<<<1024, 256, 0, stream>>>(Sg, Tg, c0buf, batch_sums);
        int nfin = (BATCHES * SEQ * SEQ) / (256 * 8);
        finalize_half<<<nfin, 256, 0, stream>>>(out, c0buf, batch_sums,
                                                sproj, tproj, cterm, alpha);
    } else {
        proj_kernel<<<4097, 256, 0, stream>>>(S, T, W, bcost, temb, taskid,
                                              sproj, tproj, cterm);
        gemm_fused_bf16<<<512, 256, 0, stream>>>(S, T, out, batch_sums);
        int nfin = (BATCHES * SEQ * SEQ) / (256 * 4);
        finalize_f32<<<nfin, 256, 0, stream>>>(out, batch_sums, sproj, tproj,
                                               cterm, alpha);
    }
}